// Round 2
// baseline (1481.149 us; speedup 1.0000x reference)
//
#include <hip/hip_runtime.h>
#include <hip/hip_bf16.h>

#define BATCH 2048
#define RES   7
#define NPOS  49
#define CDIM  512
#define HEADS 4
#define KD    32
#define DDIM  128
#define QO    192
#define EPS   1e-5f

// ---- LDS strides (element units). All fragment rows 16B-aligned; bank step
// per row = 4 dwords (gcd(stride_dwords,32)=4 or 2) -> worst 2-way = free.
#define FSTR 132   // feat [49][132] fp32
#define QSTR 36    // qbuf/qcv/kbuf [49][36] fp32
#define ASTR 68    // att  [49][68] fp32
#define VSTR 72    // vTh/vTl [128][72] bf16 (stride 144B, 16B-mult, 36 dwords)

// ---- LDS byte layout (total 76848 B -> 2 blocks/CU on 160KB LDS)
// U region (25872B = feat[49][132]):  feat  |  overlay: qcv@0 (7056) + att@7056 (13328)
//   old-feat is dead from end-of-P2 until P6 rewrites it; qcv/att live in that window.
#define OFF_QCV  0
#define OFF_ATT  7056
#define OFF_QBUF 25872
#define OFF_KBUF 32928
#define OFF_VTH  39984
#define OFF_VTL  58416
#define SMEM_SZ  76848

typedef __attribute__((ext_vector_type(8))) short short8;   // 8 bf16
typedef __attribute__((ext_vector_type(4))) float floatx4;  // 4 fp32 acc

union S8u { short8 v; __hip_bfloat162 h[4]; };
union BU  { __hip_bfloat16 b; unsigned short u; };

__device__ inline short8 pack_bf16x8(float4 a, float4 b) {
    S8u u;
    u.h[0] = __float22bfloat162_rn(make_float2(a.x, a.y));
    u.h[1] = __float22bfloat162_rn(make_float2(a.z, a.w));
    u.h[2] = __float22bfloat162_rn(make_float2(b.x, b.y));
    u.h[3] = __float22bfloat162_rn(make_float2(b.z, b.w));
    return u.v;
}

// Error-compensated split: x = hi + lo (both bf16). A*B ~= Ah*Bh + Al*Bh + Ah*Bl.
__device__ inline void split_pack8(float4 a, float4 b, short8& hi, short8& lo) {
    S8u H, L;
    float v0[8] = {a.x, a.y, a.z, a.w, b.x, b.y, b.z, b.w};
    #pragma unroll
    for (int p = 0; p < 4; ++p) {
        __hip_bfloat162 hp = __float22bfloat162_rn(make_float2(v0[2*p], v0[2*p+1]));
        float h0 = __bfloat162float(hp.x);
        float h1 = __bfloat162float(hp.y);
        H.h[p] = hp;
        L.h[p] = __float22bfloat162_rn(make_float2(v0[2*p] - h0, v0[2*p+1] - h1));
    }
    hi = H.v; lo = L.v;
}

#define MFMA(a, b, c) __builtin_amdgcn_mfma_f32_16x16x32_bf16((a), (b), (c), 0, 0, 0)

// One block per batch, 512 threads = 8 waves, 76.8KB LDS -> 2 blocks/CU.
// Attention phases: wave = (mt = wid&3, nh = wid>>2). Proj: wave owns N cols
// [64*wid, 64*wid+64) for all M (proj_w read exactly once per block).
// Fragment layouts (harness-verified): A[m=l15][k=quad*8+j], B[n=l15][k=quad*8+j],
// C/D[row=quad*4+r][col=l15]. Garbage in pad rows/cols (49..63) only reaches
// discarded D rows/cols; att K-cols 49..63 and vT K-cols 49..63 are explicit zeros.
__global__ __launch_bounds__(512, 4) void fused_cga_kernel(
    const float* __restrict__ x,
    const float* __restrict__ qkv_w,
    const float* __restrict__ qkv_g,  const float* __restrict__ qkv_bb,
    const float* __restrict__ qkv_m,  const float* __restrict__ qkv_v,
    const float* __restrict__ dw_w,
    const float* __restrict__ dw_g,   const float* __restrict__ dw_bb,
    const float* __restrict__ dw_m,   const float* __restrict__ dw_v,
    const float* __restrict__ proj_w,
    const float* __restrict__ proj_g, const float* __restrict__ proj_bb,
    const float* __restrict__ proj_m, const float* __restrict__ proj_v,
    const float* __restrict__ attn_bias,
    const int*   __restrict__ bias_idxs,
    float* __restrict__ out)
{
    __shared__ __align__(16) unsigned char smem[SMEM_SZ];
    float* feat = (float*)smem;                         // [49][FSTR]
    float* qcv  = (float*)(smem + OFF_QCV);             // [49][QSTR] (overlay in feat)
    float* att  = (float*)(smem + OFF_ATT);             // [49][ASTR] (overlay in feat)
    float* qbuf = (float*)(smem + OFF_QBUF);            // [49][QSTR]
    float* kbuf = (float*)(smem + OFF_KBUF);            // [49][QSTR]
    unsigned short* vTh = (unsigned short*)(smem + OFF_VTH);  // [128][VSTR]
    unsigned short* vTl = (unsigned short*)(smem + OFF_VTL);  // [128][VSTR]

    const int b    = blockIdx.x;
    const int tid  = threadIdx.x;
    const int lane = tid & 63;
    const int wid  = tid >> 6;
    const int quad = lane >> 4;
    const int l15  = lane & 15;
    const int mt   = wid & 3;
    const int nh   = wid >> 2;

    const float* xb = x + (size_t)b * NPOS * CDIM;

    // Persistent proj accumulators: po[mt*4+j] = rows mt*16.., cols 64*wid+j*16..
    floatx4 po[16];
    #pragma unroll
    for (int t = 0; t < 16; ++t) po[t] = (floatx4){0.f, 0.f, 0.f, 0.f};

    // One-time: zero vT K-pad cols 49..63 (hi+lo) — stays zero all heads.
    for (int i = tid; i < 128 * 15; i += 512) {
        int d = i / 15, c = 49 + (i - d * 15);
        vTh[d * VSTR + c] = 0;
        vTl[d * VSTR + c] = 0;
    }

    for (int head = 0; head < HEADS; ++head) {
        // ---- P1: cascade feat update (feat = prev PV-out + x chunk)
        for (int i = tid; i < NPOS * (DDIM / 4); i += 512) {
            int n = i >> 5, c4 = i & 31;
            float4 xv = *(const float4*)(xb + n * CDIM + head * DDIM + c4 * 4);
            float* fp = feat + n * FSTR + c4 * 4;
            if (head == 0) { *(float4*)fp = xv; }
            else {
                float4 f = *(float4*)fp;
                f.x += xv.x; f.y += xv.y; f.z += xv.z; f.w += xv.w;
                *(float4*)fp = f;
            }
        }
        __syncthreads();

        // ---- P2: QKV = feat @ Wqkv^T (M=64pad, N=192, K=128), split-bf16 MFMA.
        // B fragments straight from global (L1-resident slice); barrier-free ks loop.
        {
            floatx4 qa[6];
            #pragma unroll
            for (int t = 0; t < 6; ++t) qa[t] = (floatx4){0.f, 0.f, 0.f, 0.f};
            for (int ks = 0; ks < 4; ++ks) {
                const float* ap = feat + (mt * 16 + l15) * FSTR + ks * 32 + quad * 8;
                short8 ah, al;
                split_pack8(*(const float4*)ap, *(const float4*)(ap + 4), ah, al);
                #pragma unroll
                for (int t = 0; t < 6; ++t) {
                    const float* wp = qkv_w
                        + (size_t)(head * QO + nh * 96 + t * 16 + l15) * DDIM + ks * 32 + quad * 8;
                    short8 bh, bl;
                    split_pack8(*(const float4*)wp, *(const float4*)(wp + 4), bh, bl);
                    qa[t] = MFMA(ah, bh, qa[t]);
                    qa[t] = MFMA(al, bh, qa[t]);
                    qa[t] = MFMA(ah, bl, qa[t]);
                }
            }
            // epilogue: BN (params direct from global) then route q / k / v(split, transposed)
            #pragma unroll
            for (int t = 0; t < 6; ++t) {
                int o   = nh * 96 + t * 16 + l15;
                int idx = head * QO + o;
                float s  = qkv_g[idx] * rsqrtf(qkv_v[idx] + EPS);
                float tt = qkv_bb[idx] - qkv_m[idx] * s;
                #pragma unroll
                for (int r = 0; r < 4; ++r) {
                    int row = mt * 16 + quad * 4 + r;
                    if (row < NPOS) {
                        float y = qa[t][r] * s + tt;
                        if (o < KD)          qbuf[row * QSTR + o] = y;
                        else if (o < 2 * KD) kbuf[row * QSTR + (o - KD)] = y;
                        else {
                            int d = o - 2 * KD;
                            BU hu, lu;
                            __hip_bfloat162 hp = __float22bfloat162_rn(make_float2(y, 0.f));
                            hu.b = hp.x;
                            float hf = __bfloat162float(hp.x);
                            __hip_bfloat162 lp = __float22bfloat162_rn(make_float2(y - hf, 0.f));
                            lu.b = lp.x;
                            vTh[d * VSTR + row] = hu.u;
                            vTl[d * VSTR + row] = lu.u;
                        }
                    }
                }
            }
        }
        __syncthreads();

        // ---- P3: depthwise 5x5 conv + BN -> qcv (fp32, params/weights from global)
        for (int i = tid; i < NPOS * KD; i += 512) {
            int n = i >> 5, ch = i & 31;
            int rr = n / RES, cc = n - rr * RES;
            const float* wd = dw_w + (size_t)(head * KD + ch) * 25;
            float acc = 0.f;
            #pragma unroll
            for (int dy = 0; dy < 5; ++dy) {
                int ry = rr + dy - 2;
                if (ry < 0 || ry >= RES) continue;
                #pragma unroll
                for (int dx = 0; dx < 5; ++dx) {
                    int cx = cc + dx - 2;
                    if (cx < 0 || cx >= RES) continue;
                    acc += qbuf[(ry * RES + cx) * QSTR + ch] * wd[dy * 5 + dx];
                }
            }
            int idx = head * KD + ch;
            float s  = dw_g[idx] * rsqrtf(dw_v[idx] + EPS);
            float tt = dw_bb[idx] - dw_m[idx] * s;
            qcv[n * QSTR + ch] = acc * s + tt;
        }
        __syncthreads();

        // ---- P4: att = qcv @ kbuf^T * scale + bias (M=64pad, N=64pad, K=32)
        {
            floatx4 sa[2];
            sa[0] = (floatx4){0.f, 0.f, 0.f, 0.f};
            sa[1] = (floatx4){0.f, 0.f, 0.f, 0.f};
            const float* ap = qcv + (mt * 16 + l15) * QSTR + quad * 8;
            short8 ah, al;
            split_pack8(*(const float4*)ap, *(const float4*)(ap + 4), ah, al);
            #pragma unroll
            for (int t = 0; t < 2; ++t) {
                const float* kp = kbuf + ((nh * 2 + t) * 16 + l15) * QSTR + quad * 8;
                short8 bh, bl;
                split_pack8(*(const float4*)kp, *(const float4*)(kp + 4), bh, bl);
                sa[t] = MFMA(ah, bh, sa[t]);
                sa[t] = MFMA(al, bh, sa[t]);
                sa[t] = MFMA(ah, bl, sa[t]);
            }
            const float scale = 0.17677669529663687f;
            #pragma unroll
            for (int t = 0; t < 2; ++t) {
                int nn = (nh * 2 + t) * 16 + l15;
                #pragma unroll
                for (int r = 0; r < 4; ++r) {
                    int row = mt * 16 + quad * 4 + r;
                    if (row < NPOS) {
                        if (nn < NPOS)
                            att[row * ASTR + nn] = sa[t][r] * scale
                                + attn_bias[head * NPOS + bias_idxs[row * NPOS + nn]];
                        else
                            att[row * ASTR + nn] = 0.f;   // K-pad for PV
                    }
                }
            }
        }
        __syncthreads();

        // ---- P5: softmax (8 lanes/row, shfl-xor reduce)
        {
            int row = tid >> 3, g = tid & 7;
            if (row < NPOS) {
                float mx = -1e30f;
                for (int n = g; n < NPOS; n += 8) mx = fmaxf(mx, att[row * ASTR + n]);
                #pragma unroll
                for (int d = 1; d < 8; d <<= 1) mx = fmaxf(mx, __shfl_xor(mx, d));
                float sm = 0.f;
                for (int n = g; n < NPOS; n += 8) {
                    float e = __expf(att[row * ASTR + n] - mx);
                    att[row * ASTR + n] = e;
                    sm += e;
                }
                #pragma unroll
                for (int d = 1; d < 8; d <<= 1) sm += __shfl_xor(sm, d);
                float inv = 1.f / sm;
                for (int n = g; n < NPOS; n += 8) att[row * ASTR + n] *= inv;
            }
        }
        __syncthreads();

        // ---- P6: feat = att @ v (M=64pad, N=128, K=64). att overlays feat, so:
        // read ALL att A-frags -> barrier -> MFMA + write feat.
        {
            short8 ah[2], al[2];
            #pragma unroll
            for (int ks = 0; ks < 2; ++ks) {
                const float* ap = att + (mt * 16 + l15) * ASTR + ks * 32 + quad * 8;
                split_pack8(*(const float4*)ap, *(const float4*)(ap + 4), ah[ks], al[ks]);
            }
            __syncthreads();   // all att reads done before feat overwrite
            floatx4 pa[4];
            #pragma unroll
            for (int t = 0; t < 4; ++t) pa[t] = (floatx4){0.f, 0.f, 0.f, 0.f};
            #pragma unroll
            for (int ks = 0; ks < 2; ++ks) {
                #pragma unroll
                for (int t = 0; t < 4; ++t) {
                    int off = ((nh * 4 + t) * 16 + l15) * VSTR + ks * 32 + quad * 8;
                    short8 bh = *(const short8*)(vTh + off);
                    short8 bl = *(const short8*)(vTl + off);
                    pa[t] = MFMA(ah[ks], bh, pa[t]);
                    pa[t] = MFMA(al[ks], bh, pa[t]);
                    pa[t] = MFMA(ah[ks], bl, pa[t]);
                }
            }
            #pragma unroll
            for (int t = 0; t < 4; ++t) {
                int d = (nh * 4 + t) * 16 + l15;
                #pragma unroll
                for (int r = 0; r < 4; ++r) {
                    int row = mt * 16 + quad * 4 + r;
                    if (row < NPOS) feat[row * FSTR + d] = pa[t][r];
                }
            }
        }
        __syncthreads();

        // ---- P7: po += bf16(relu(feat)) @ bf16(proj_w rows [64*wid..+64))^T
        // 8-way N-split: proj_w read once per block; barrier-free ks loop.
        {
            const int nbase = wid * 64;
            for (int ks = 0; ks < 4; ++ks) {
                short8 af[4];
                #pragma unroll
                for (int mm = 0; mm < 4; ++mm) {
                    const float* ap = feat + (mm * 16 + l15) * FSTR + ks * 32 + quad * 8;
                    float4 a0 = *(const float4*)ap;
                    float4 a1 = *(const float4*)(ap + 4);
                    a0.x = fmaxf(a0.x, 0.f); a0.y = fmaxf(a0.y, 0.f);
                    a0.z = fmaxf(a0.z, 0.f); a0.w = fmaxf(a0.w, 0.f);
                    a1.x = fmaxf(a1.x, 0.f); a1.y = fmaxf(a1.y, 0.f);
                    a1.z = fmaxf(a1.z, 0.f); a1.w = fmaxf(a1.w, 0.f);
                    af[mm] = pack_bf16x8(a0, a1);
                }
                #pragma unroll
                for (int j = 0; j < 4; ++j) {
                    const float* wp = proj_w
                        + (size_t)(nbase + j * 16 + l15) * CDIM + head * DDIM + ks * 32 + quad * 8;
                    short8 bf = pack_bf16x8(*(const float4*)wp, *(const float4*)(wp + 4));
                    #pragma unroll
                    for (int mm = 0; mm < 4; ++mm)
                        po[mm * 4 + j] = MFMA(af[mm], bf, po[mm * 4 + j]);
                }
            }
        }
        __syncthreads();   // feat reads done before next head's P1 rewrite
    }

    // ---- final epilogue: proj BN (params from global) + store
    {
        const int nbase = wid * 64;
        #pragma unroll
        for (int j = 0; j < 4; ++j) {
            int o = nbase + j * 16 + l15;
            float s  = proj_g[o] * rsqrtf(proj_v[o] + EPS);
            float tt = proj_bb[o] - proj_m[o] * s;
            #pragma unroll
            for (int mm = 0; mm < 4; ++mm) {
                #pragma unroll
                for (int r = 0; r < 4; ++r) {
                    int row = mm * 16 + quad * 4 + r;
                    if (row < NPOS)
                        out[((size_t)b * NPOS + row) * CDIM + o] = po[mm * 4 + j][r] * s + tt;
                }
            }
        }
    }
}

// ---------------------------------------------------------------------------
extern "C" void kernel_launch(void* const* d_in, const int* in_sizes, int n_in,
                              void* d_out, int out_size, void* d_ws, size_t ws_size,
                              hipStream_t stream) {
    const float* x      = (const float*)d_in[0];
    const float* qkv_w  = (const float*)d_in[1];
    const float* qkv_g  = (const float*)d_in[2];
    const float* qkv_b  = (const float*)d_in[3];
    const float* qkv_m  = (const float*)d_in[4];
    const float* qkv_v  = (const float*)d_in[5];
    const float* dw_w   = (const float*)d_in[6];
    const float* dw_g   = (const float*)d_in[7];
    const float* dw_b   = (const float*)d_in[8];
    const float* dw_m   = (const float*)d_in[9];
    const float* dw_v   = (const float*)d_in[10];
    const float* proj_w = (const float*)d_in[11];
    const float* proj_g = (const float*)d_in[12];
    const float* proj_b = (const float*)d_in[13];
    const float* proj_m = (const float*)d_in[14];
    const float* proj_v = (const float*)d_in[15];
    const float* attn_bias = (const float*)d_in[16];
    const int*   bias_idxs = (const int*)d_in[17];
    float* out = (float*)d_out;
    (void)d_ws; (void)ws_size;   // R2 lesson: d_ws too small — unused.

    hipLaunchKernelGGL(fused_cga_kernel, dim3(BATCH), dim3(512), 0, stream,
        x, qkv_w, qkv_g, qkv_b, qkv_m, qkv_v,
        dw_w, dw_g, dw_b, dw_m, dw_v,
        proj_w, proj_g, proj_b, proj_m, proj_v,
        attn_bias, bias_idxs, out);
}

// Round 3
// 1429.469 us; speedup vs baseline: 1.0362x; 1.0362x over previous
//
#include <hip/hip_runtime.h>
#include <hip/hip_bf16.h>

#define BATCH 2048
#define RES   7
#define NPOS  49
#define CDIM  512
#define HEADS 4
#define KD    32
#define DDIM  128
#define QO    192
#define EPS   1e-5f

// ---- LDS strides (element units). All fragment rows 16B-aligned; bank step
// per row = 4 dwords (gcd(stride_dwords,32)=4 or 2) -> worst 2-way = free.
#define FSTR 132   // feat [49][132] fp32
#define QSTR 36    // qbuf/qcv/kbuf [49][36] fp32
#define ASTR 68    // att  [49][68] fp32
#define VSTR 72    // vTh/vTl [128][72] bf16 (stride 144B, 16B-mult, 36 dwords)

// ---- LDS byte layout (total 76848 B -> 2 blocks/CU on 160KB LDS)
// U region (25872B = feat[49][132]):  feat  |  overlay: qcv@0 (7056) + att@7056 (13328)
//   old-feat is dead from end-of-P2 until P6 rewrites it; qcv/att live in that window.
#define OFF_QCV  0
#define OFF_ATT  7056
#define OFF_QBUF 25872
#define OFF_KBUF 32928
#define OFF_VTH  39984
#define OFF_VTL  58416
#define SMEM_SZ  76848

typedef __attribute__((ext_vector_type(8))) short short8;   // 8 bf16
typedef __attribute__((ext_vector_type(4))) float floatx4;  // 4 fp32 acc

union S8u { short8 v; __hip_bfloat162 h[4]; };
union BU  { __hip_bfloat16 b; unsigned short u; };

__device__ inline short8 pack_bf16x8(float4 a, float4 b) {
    S8u u;
    u.h[0] = __float22bfloat162_rn(make_float2(a.x, a.y));
    u.h[1] = __float22bfloat162_rn(make_float2(a.z, a.w));
    u.h[2] = __float22bfloat162_rn(make_float2(b.x, b.y));
    u.h[3] = __float22bfloat162_rn(make_float2(b.z, b.w));
    return u.v;
}

// Error-compensated split: x = hi + lo (both bf16). A*B ~= Ah*Bh + Al*Bh + Ah*Bl.
__device__ inline void split_pack8(float4 a, float4 b, short8& hi, short8& lo) {
    S8u H, L;
    float v0[8] = {a.x, a.y, a.z, a.w, b.x, b.y, b.z, b.w};
    #pragma unroll
    for (int p = 0; p < 4; ++p) {
        __hip_bfloat162 hp = __float22bfloat162_rn(make_float2(v0[2*p], v0[2*p+1]));
        float h0 = __bfloat162float(hp.x);
        float h1 = __bfloat162float(hp.y);
        H.h[p] = hp;
        L.h[p] = __float22bfloat162_rn(make_float2(v0[2*p] - h0, v0[2*p+1] - h1));
    }
    hi = H.v; lo = L.v;
}

#define MFMA(a, b, c) __builtin_amdgcn_mfma_f32_16x16x32_bf16((a), (b), (c), 0, 0, 0)

// One block per batch, 512 threads = 8 waves, 76.8KB LDS.
// __launch_bounds__(512, 2): VGPR cap 128 (po[16]=64 + P2 live set ~120 fits).
// R2 lesson: (512,4) capped VGPR at 64 -> po[16] spilled to scratch -> +760MB/dispatch
// HBM traffic and 1.5x slowdown. 2 blocks/CU needs VGPR<=128 + LDS<=80KB, both met here.
// Attention phases: wave = (mt = wid&3, nh = wid>>2). Proj: wave owns N cols
// [64*wid, 64*wid+64) for all M (proj_w read exactly once per block).
// Fragment layouts (harness-verified): A[m=l15][k=quad*8+j], B[n=l15][k=quad*8+j],
// C/D[row=quad*4+r][col=l15]. Garbage in pad rows/cols (49..63) only reaches
// discarded D rows/cols; att K-cols 49..63 and vT K-cols 49..63 are explicit zeros.
__global__ __launch_bounds__(512, 2) void fused_cga_kernel(
    const float* __restrict__ x,
    const float* __restrict__ qkv_w,
    const float* __restrict__ qkv_g,  const float* __restrict__ qkv_bb,
    const float* __restrict__ qkv_m,  const float* __restrict__ qkv_v,
    const float* __restrict__ dw_w,
    const float* __restrict__ dw_g,   const float* __restrict__ dw_bb,
    const float* __restrict__ dw_m,   const float* __restrict__ dw_v,
    const float* __restrict__ proj_w,
    const float* __restrict__ proj_g, const float* __restrict__ proj_bb,
    const float* __restrict__ proj_m, const float* __restrict__ proj_v,
    const float* __restrict__ attn_bias,
    const int*   __restrict__ bias_idxs,
    float* __restrict__ out)
{
    __shared__ __align__(16) unsigned char smem[SMEM_SZ];
    float* feat = (float*)smem;                         // [49][FSTR]
    float* qcv  = (float*)(smem + OFF_QCV);             // [49][QSTR] (overlay in feat)
    float* att  = (float*)(smem + OFF_ATT);             // [49][ASTR] (overlay in feat)
    float* qbuf = (float*)(smem + OFF_QBUF);            // [49][QSTR]
    float* kbuf = (float*)(smem + OFF_KBUF);            // [49][QSTR]
    unsigned short* vTh = (unsigned short*)(smem + OFF_VTH);  // [128][VSTR]
    unsigned short* vTl = (unsigned short*)(smem + OFF_VTL);  // [128][VSTR]

    const int b    = blockIdx.x;
    const int tid  = threadIdx.x;
    const int lane = tid & 63;
    const int wid  = tid >> 6;
    const int quad = lane >> 4;
    const int l15  = lane & 15;
    const int mt   = wid & 3;
    const int nh   = wid >> 2;

    const float* xb = x + (size_t)b * NPOS * CDIM;

    // Persistent proj accumulators: po[mm*4+j] = rows mm*16.., cols 64*wid+j*16..
    floatx4 po[16];
    #pragma unroll
    for (int t = 0; t < 16; ++t) po[t] = (floatx4){0.f, 0.f, 0.f, 0.f};

    // One-time: zero vT K-pad cols 49..63 (hi+lo) — stays zero all heads.
    for (int i = tid; i < 128 * 15; i += 512) {
        int d = i / 15, c = 49 + (i - d * 15);
        vTh[d * VSTR + c] = 0;
        vTl[d * VSTR + c] = 0;
    }

    for (int head = 0; head < HEADS; ++head) {
        // ---- P1: cascade feat update (feat = prev PV-out + x chunk)
        for (int i = tid; i < NPOS * (DDIM / 4); i += 512) {
            int n = i >> 5, c4 = i & 31;
            float4 xv = *(const float4*)(xb + n * CDIM + head * DDIM + c4 * 4);
            float* fp = feat + n * FSTR + c4 * 4;
            if (head == 0) { *(float4*)fp = xv; }
            else {
                float4 f = *(float4*)fp;
                f.x += xv.x; f.y += xv.y; f.z += xv.z; f.w += xv.w;
                *(float4*)fp = f;
            }
        }
        __syncthreads();

        // ---- P2: QKV = feat @ Wqkv^T (M=64pad, N=192, K=128), split-bf16 MFMA.
        // B fragments straight from global (L1-resident slice); barrier-free ks loop.
        {
            floatx4 qa[6];
            #pragma unroll
            for (int t = 0; t < 6; ++t) qa[t] = (floatx4){0.f, 0.f, 0.f, 0.f};
            for (int ks = 0; ks < 4; ++ks) {
                const float* ap = feat + (mt * 16 + l15) * FSTR + ks * 32 + quad * 8;
                short8 ah, al;
                split_pack8(*(const float4*)ap, *(const float4*)(ap + 4), ah, al);
                #pragma unroll
                for (int t = 0; t < 6; ++t) {
                    const float* wp = qkv_w
                        + (size_t)(head * QO + nh * 96 + t * 16 + l15) * DDIM + ks * 32 + quad * 8;
                    short8 bh, bl;
                    split_pack8(*(const float4*)wp, *(const float4*)(wp + 4), bh, bl);
                    qa[t] = MFMA(ah, bh, qa[t]);
                    qa[t] = MFMA(al, bh, qa[t]);
                    qa[t] = MFMA(ah, bl, qa[t]);
                }
            }
            // epilogue: BN (params direct from global) then route q / k / v(split, transposed)
            #pragma unroll
            for (int t = 0; t < 6; ++t) {
                int o   = nh * 96 + t * 16 + l15;
                int idx = head * QO + o;
                float s  = qkv_g[idx] * rsqrtf(qkv_v[idx] + EPS);
                float tt = qkv_bb[idx] - qkv_m[idx] * s;
                #pragma unroll
                for (int r = 0; r < 4; ++r) {
                    int row = mt * 16 + quad * 4 + r;
                    if (row < NPOS) {
                        float y = qa[t][r] * s + tt;
                        if (o < KD)          qbuf[row * QSTR + o] = y;
                        else if (o < 2 * KD) kbuf[row * QSTR + (o - KD)] = y;
                        else {
                            int d = o - 2 * KD;
                            BU hu, lu;
                            __hip_bfloat162 hp = __float22bfloat162_rn(make_float2(y, 0.f));
                            hu.b = hp.x;
                            float hf = __bfloat162float(hp.x);
                            __hip_bfloat162 lp = __float22bfloat162_rn(make_float2(y - hf, 0.f));
                            lu.b = lp.x;
                            vTh[d * VSTR + row] = hu.u;
                            vTl[d * VSTR + row] = lu.u;
                        }
                    }
                }
            }
        }
        __syncthreads();

        // ---- P3: depthwise 5x5 conv + BN -> qcv (fp32, params/weights from global)
        for (int i = tid; i < NPOS * KD; i += 512) {
            int n = i >> 5, ch = i & 31;
            int rr = n / RES, cc = n - rr * RES;
            const float* wd = dw_w + (size_t)(head * KD + ch) * 25;
            float acc = 0.f;
            #pragma unroll
            for (int dy = 0; dy < 5; ++dy) {
                int ry = rr + dy - 2;
                if (ry < 0 || ry >= RES) continue;
                #pragma unroll
                for (int dx = 0; dx < 5; ++dx) {
                    int cx = cc + dx - 2;
                    if (cx < 0 || cx >= RES) continue;
                    acc += qbuf[(ry * RES + cx) * QSTR + ch] * wd[dy * 5 + dx];
                }
            }
            int idx = head * KD + ch;
            float s  = dw_g[idx] * rsqrtf(dw_v[idx] + EPS);
            float tt = dw_bb[idx] - dw_m[idx] * s;
            qcv[n * QSTR + ch] = acc * s + tt;
        }
        __syncthreads();

        // ---- P4: att = qcv @ kbuf^T * scale + bias (M=64pad, N=64pad, K=32)
        {
            floatx4 sa[2];
            sa[0] = (floatx4){0.f, 0.f, 0.f, 0.f};
            sa[1] = (floatx4){0.f, 0.f, 0.f, 0.f};
            const float* ap = qcv + (mt * 16 + l15) * QSTR + quad * 8;
            short8 ah, al;
            split_pack8(*(const float4*)ap, *(const float4*)(ap + 4), ah, al);
            #pragma unroll
            for (int t = 0; t < 2; ++t) {
                const float* kp = kbuf + ((nh * 2 + t) * 16 + l15) * QSTR + quad * 8;
                short8 bh, bl;
                split_pack8(*(const float4*)kp, *(const float4*)(kp + 4), bh, bl);
                sa[t] = MFMA(ah, bh, sa[t]);
                sa[t] = MFMA(al, bh, sa[t]);
                sa[t] = MFMA(ah, bl, sa[t]);
            }
            const float scale = 0.17677669529663687f;
            #pragma unroll
            for (int t = 0; t < 2; ++t) {
                int nn = (nh * 2 + t) * 16 + l15;
                #pragma unroll
                for (int r = 0; r < 4; ++r) {
                    int row = mt * 16 + quad * 4 + r;
                    if (row < NPOS) {
                        if (nn < NPOS)
                            att[row * ASTR + nn] = sa[t][r] * scale
                                + attn_bias[head * NPOS + bias_idxs[row * NPOS + nn]];
                        else
                            att[row * ASTR + nn] = 0.f;   // K-pad for PV
                    }
                }
            }
        }
        __syncthreads();

        // ---- P5: softmax (8 lanes/row, shfl-xor reduce)
        {
            int row = tid >> 3, g = tid & 7;
            if (row < NPOS) {
                float mx = -1e30f;
                for (int n = g; n < NPOS; n += 8) mx = fmaxf(mx, att[row * ASTR + n]);
                #pragma unroll
                for (int d = 1; d < 8; d <<= 1) mx = fmaxf(mx, __shfl_xor(mx, d));
                float sm = 0.f;
                for (int n = g; n < NPOS; n += 8) {
                    float e = __expf(att[row * ASTR + n] - mx);
                    att[row * ASTR + n] = e;
                    sm += e;
                }
                #pragma unroll
                for (int d = 1; d < 8; d <<= 1) sm += __shfl_xor(sm, d);
                float inv = 1.f / sm;
                for (int n = g; n < NPOS; n += 8) att[row * ASTR + n] *= inv;
            }
        }
        __syncthreads();

        // ---- P6: feat = att @ v (M=64pad, N=128, K=64). att overlays feat, so:
        // read ALL att A-frags -> barrier -> MFMA + write feat.
        {
            short8 ah[2], al[2];
            #pragma unroll
            for (int ks = 0; ks < 2; ++ks) {
                const float* ap = att + (mt * 16 + l15) * ASTR + ks * 32 + quad * 8;
                split_pack8(*(const float4*)ap, *(const float4*)(ap + 4), ah[ks], al[ks]);
            }
            __syncthreads();   // all att reads done before feat overwrite
            floatx4 pa[4];
            #pragma unroll
            for (int t = 0; t < 4; ++t) pa[t] = (floatx4){0.f, 0.f, 0.f, 0.f};
            #pragma unroll
            for (int ks = 0; ks < 2; ++ks) {
                #pragma unroll
                for (int t = 0; t < 4; ++t) {
                    int off = ((nh * 4 + t) * 16 + l15) * VSTR + ks * 32 + quad * 8;
                    short8 bh = *(const short8*)(vTh + off);
                    short8 bl = *(const short8*)(vTl + off);
                    pa[t] = MFMA(ah[ks], bh, pa[t]);
                    pa[t] = MFMA(al[ks], bh, pa[t]);
                    pa[t] = MFMA(ah[ks], bl, pa[t]);
                }
            }
            #pragma unroll
            for (int t = 0; t < 4; ++t) {
                int d = (nh * 4 + t) * 16 + l15;
                #pragma unroll
                for (int r = 0; r < 4; ++r) {
                    int row = mt * 16 + quad * 4 + r;
                    if (row < NPOS) feat[row * FSTR + d] = pa[t][r];
                }
            }
        }
        __syncthreads();

        // ---- P7: po += bf16(relu(feat)) @ bf16(proj_w rows [64*wid..+64))^T
        // 8-way N-split: proj_w read once per block; barrier-free ks loop.
        {
            const int nbase = wid * 64;
            for (int ks = 0; ks < 4; ++ks) {
                short8 af[4];
                #pragma unroll
                for (int mm = 0; mm < 4; ++mm) {
                    const float* ap = feat + (mm * 16 + l15) * FSTR + ks * 32 + quad * 8;
                    float4 a0 = *(const float4*)ap;
                    float4 a1 = *(const float4*)(ap + 4);
                    a0.x = fmaxf(a0.x, 0.f); a0.y = fmaxf(a0.y, 0.f);
                    a0.z = fmaxf(a0.z, 0.f); a0.w = fmaxf(a0.w, 0.f);
                    a1.x = fmaxf(a1.x, 0.f); a1.y = fmaxf(a1.y, 0.f);
                    a1.z = fmaxf(a1.z, 0.f); a1.w = fmaxf(a1.w, 0.f);
                    af[mm] = pack_bf16x8(a0, a1);
                }
                #pragma unroll
                for (int j = 0; j < 4; ++j) {
                    const float* wp = proj_w
                        + (size_t)(nbase + j * 16 + l15) * CDIM + head * DDIM + ks * 32 + quad * 8;
                    short8 bf = pack_bf16x8(*(const float4*)wp, *(const float4*)(wp + 4));
                    #pragma unroll
                    for (int mm = 0; mm < 4; ++mm)
                        po[mm * 4 + j] = MFMA(af[mm], bf, po[mm * 4 + j]);
                }
            }
        }
        __syncthreads();   // feat reads done before next head's P1 rewrite
    }

    // ---- final epilogue: proj BN (params from global) + store
    {
        const int nbase = wid * 64;
        #pragma unroll
        for (int j = 0; j < 4; ++j) {
            int o = nbase + j * 16 + l15;
            float s  = proj_g[o] * rsqrtf(proj_v[o] + EPS);
            float tt = proj_bb[o] - proj_m[o] * s;
            #pragma unroll
            for (int mm = 0; mm < 4; ++mm) {
                #pragma unroll
                for (int r = 0; r < 4; ++r) {
                    int row = mm * 16 + quad * 4 + r;
                    if (row < NPOS)
                        out[((size_t)b * NPOS + row) * CDIM + o] = po[mm * 4 + j][r] * s + tt;
                }
            }
        }
    }
}

// ---------------------------------------------------------------------------
extern "C" void kernel_launch(void* const* d_in, const int* in_sizes, int n_in,
                              void* d_out, int out_size, void* d_ws, size_t ws_size,
                              hipStream_t stream) {
    const float* x      = (const float*)d_in[0];
    const float* qkv_w  = (const float*)d_in[1];
    const float* qkv_g  = (const float*)d_in[2];
    const float* qkv_b  = (const float*)d_in[3];
    const float* qkv_m  = (const float*)d_in[4];
    const float* qkv_v  = (const float*)d_in[5];
    const float* dw_w   = (const float*)d_in[6];
    const float* dw_g   = (const float*)d_in[7];
    const float* dw_b   = (const float*)d_in[8];
    const float* dw_m   = (const float*)d_in[9];
    const float* dw_v   = (const float*)d_in[10];
    const float* proj_w = (const float*)d_in[11];
    const float* proj_g = (const float*)d_in[12];
    const float* proj_b = (const float*)d_in[13];
    const float* proj_m = (const float*)d_in[14];
    const float* proj_v = (const float*)d_in[15];
    const float* attn_bias = (const float*)d_in[16];
    const int*   bias_idxs = (const int*)d_in[17];
    float* out = (float*)d_out;
    (void)d_ws; (void)ws_size;   // d_ws too small — unused.

    hipLaunchKernelGGL(fused_cga_kernel, dim3(BATCH), dim3(512), 0, stream,
        x, qkv_w, qkv_g, qkv_b, qkv_m, qkv_v,
        dw_w, dw_g, dw_b, dw_m, dw_v,
        proj_w, proj_g, proj_b, proj_m, proj_v,
        attn_bias, bias_idxs, out);
}

// Round 4
// 1276.602 us; speedup vs baseline: 1.1602x; 1.1197x over previous
//
#include <hip/hip_runtime.h>
#include <hip/hip_bf16.h>

#define BATCH 2048
#define RES   7
#define NPOS  49
#define CDIM  512
#define HEADS 4
#define KD    32
#define DDIM  128
#define QO    192
#define EPS   1e-5f

// ---- LDS strides (element units). All fragment rows 16B-aligned; bank step
// per row = 4 dwords (gcd(stride_dwords,32)=4) -> worst 2-way = free.
#define FSTR 132   // feat [49][132] fp32
#define QSTR 36    // qbuf/qcv/kbuf [49][36] fp32
#define ASTR 68    // att  [49][68] fp32
#define VSTR 72    // vTh/vTl [128][72] bf16

// ---- Kernel-1 LDS layout (76848 B -> 2 blocks/CU on 160KB LDS)
#define OFF_QCV  0
#define OFF_ATT  7056
#define OFF_QBUF 25872
#define OFF_KBUF 32928
#define OFF_VTH  39984
#define OFF_VTL  58416
#define SMEM_SZ  76848

#define HSTR 520   // kernel-2 h LDS stride (shorts): 1040B rows, 16B-mult, gcd(260,32)=4

typedef __attribute__((ext_vector_type(8))) short short8;   // 8 bf16
typedef __attribute__((ext_vector_type(4))) float floatx4;  // 4 fp32 acc

union S8u { short8 v; __hip_bfloat162 h[4]; };
union BU  { __hip_bfloat16 b; unsigned short u; };

__device__ inline short8 pack_bf16x8(float4 a, float4 b) {
    S8u u;
    u.h[0] = __float22bfloat162_rn(make_float2(a.x, a.y));
    u.h[1] = __float22bfloat162_rn(make_float2(a.z, a.w));
    u.h[2] = __float22bfloat162_rn(make_float2(b.x, b.y));
    u.h[3] = __float22bfloat162_rn(make_float2(b.z, b.w));
    return u.v;
}

// Error-compensated split: x = hi + lo (both bf16). A*B ~= Ah*Bh + Al*Bh + Ah*Bl.
__device__ inline void split_pack8(float4 a, float4 b, short8& hi, short8& lo) {
    S8u H, L;
    float v0[8] = {a.x, a.y, a.z, a.w, b.x, b.y, b.z, b.w};
    #pragma unroll
    for (int p = 0; p < 4; ++p) {
        __hip_bfloat162 hp = __float22bfloat162_rn(make_float2(v0[2*p], v0[2*p+1]));
        float h0 = __bfloat162float(hp.x);
        float h1 = __bfloat162float(hp.y);
        H.h[p] = hp;
        L.h[p] = __float22bfloat162_rn(make_float2(v0[2*p] - h0, v0[2*p+1] - h1));
    }
    hi = H.v; lo = L.v;
}

#define MFMA(a, b, c) __builtin_amdgcn_mfma_f32_16x16x32_bf16((a), (b), (c), 0, 0, 0)

// ===========================================================================
// Kernel 1: cascade + QKV + conv + attention. One block/batch, 512 thr = 8 waves.
// R3 lesson: persistent proj accumulators (64 AGPRs) pushed total regs to ~164
// -> only 1 block/CU. Proj removed from this kernel entirely; per head we write
// h = bf16(relu(feat)) into d_out's OWN batch region (bf16 h = 100352 B fits in
// the 401408 B fp32 out region; kernel 2 consumes it in-place, race-free).
// (512,4): total reg cap 128 — attention-only live set ~100, no spill expected.
// ===========================================================================
__global__ __launch_bounds__(512, 4) void cga_attn_kernel(
    const float* __restrict__ x,
    const float* __restrict__ qkv_w,
    const float* __restrict__ qkv_g,  const float* __restrict__ qkv_bb,
    const float* __restrict__ qkv_m,  const float* __restrict__ qkv_v,
    const float* __restrict__ dw_w,
    const float* __restrict__ dw_g,   const float* __restrict__ dw_bb,
    const float* __restrict__ dw_m,   const float* __restrict__ dw_v,
    const float* __restrict__ attn_bias,
    const int*   __restrict__ bias_idxs,
    float* __restrict__ out)
{
    __shared__ __align__(16) unsigned char smem[SMEM_SZ];
    float* feat = (float*)smem;                         // [49][FSTR]
    float* qcv  = (float*)(smem + OFF_QCV);             // [49][QSTR] (overlay in feat)
    float* att  = (float*)(smem + OFF_ATT);             // [49][ASTR] (overlay in feat)
    float* qbuf = (float*)(smem + OFF_QBUF);            // [49][QSTR]
    float* kbuf = (float*)(smem + OFF_KBUF);            // [49][QSTR]
    unsigned short* vTh = (unsigned short*)(smem + OFF_VTH);  // [128][VSTR]
    unsigned short* vTl = (unsigned short*)(smem + OFF_VTL);  // [128][VSTR]

    const int b    = blockIdx.x;
    const int tid  = threadIdx.x;
    const int lane = tid & 63;
    const int wid  = tid >> 6;
    const int quad = lane >> 4;
    const int l15  = lane & 15;
    const int mt   = wid & 3;
    const int nh   = wid >> 2;

    const float* xb = x + (size_t)b * NPOS * CDIM;
    unsigned short* hb = (unsigned short*)(out + (size_t)b * NPOS * CDIM);  // bf16 h, in-place

    // One-time: zero vT K-pad cols 49..63 (hi+lo) — stays zero all heads.
    for (int i = tid; i < 128 * 15; i += 512) {
        int d = i / 15, c = 49 + (i - d * 15);
        vTh[d * VSTR + c] = 0;
        vTl[d * VSTR + c] = 0;
    }

    for (int head = 0; head < HEADS; ++head) {
        // ---- P1: cascade feat update (feat = prev PV-out + x chunk)
        for (int i = tid; i < NPOS * (DDIM / 4); i += 512) {
            int n = i >> 5, c4 = i & 31;
            float4 xv = *(const float4*)(xb + n * CDIM + head * DDIM + c4 * 4);
            float* fp = feat + n * FSTR + c4 * 4;
            if (head == 0) { *(float4*)fp = xv; }
            else {
                float4 f = *(float4*)fp;
                f.x += xv.x; f.y += xv.y; f.z += xv.z; f.w += xv.w;
                *(float4*)fp = f;
            }
        }
        __syncthreads();

        // ---- P2: QKV = feat @ Wqkv^T (M=64pad, N=192, K=128), split-bf16 MFMA.
        {
            floatx4 qa[6];
            #pragma unroll
            for (int t = 0; t < 6; ++t) qa[t] = (floatx4){0.f, 0.f, 0.f, 0.f};
            for (int ks = 0; ks < 4; ++ks) {
                const float* ap = feat + (mt * 16 + l15) * FSTR + ks * 32 + quad * 8;
                short8 ah, al;
                split_pack8(*(const float4*)ap, *(const float4*)(ap + 4), ah, al);
                #pragma unroll
                for (int t = 0; t < 6; ++t) {
                    const float* wp = qkv_w
                        + (size_t)(head * QO + nh * 96 + t * 16 + l15) * DDIM + ks * 32 + quad * 8;
                    short8 bh, bl;
                    split_pack8(*(const float4*)wp, *(const float4*)(wp + 4), bh, bl);
                    qa[t] = MFMA(ah, bh, qa[t]);
                    qa[t] = MFMA(al, bh, qa[t]);
                    qa[t] = MFMA(ah, bl, qa[t]);
                }
            }
            // epilogue: BN then route q / k / v(split, transposed)
            #pragma unroll
            for (int t = 0; t < 6; ++t) {
                int o   = nh * 96 + t * 16 + l15;
                int idx = head * QO + o;
                float s  = qkv_g[idx] * rsqrtf(qkv_v[idx] + EPS);
                float tt = qkv_bb[idx] - qkv_m[idx] * s;
                #pragma unroll
                for (int r = 0; r < 4; ++r) {
                    int row = mt * 16 + quad * 4 + r;
                    if (row < NPOS) {
                        float y = qa[t][r] * s + tt;
                        if (o < KD)          qbuf[row * QSTR + o] = y;
                        else if (o < 2 * KD) kbuf[row * QSTR + (o - KD)] = y;
                        else {
                            int d = o - 2 * KD;
                            BU hu, lu;
                            __hip_bfloat162 hp = __float22bfloat162_rn(make_float2(y, 0.f));
                            hu.b = hp.x;
                            float hf = __bfloat162float(hp.x);
                            __hip_bfloat162 lp = __float22bfloat162_rn(make_float2(y - hf, 0.f));
                            lu.b = lp.x;
                            vTh[d * VSTR + row] = hu.u;
                            vTl[d * VSTR + row] = lu.u;
                        }
                    }
                }
            }
        }
        __syncthreads();

        // ---- P3: depthwise 5x5 conv + BN -> qcv
        for (int i = tid; i < NPOS * KD; i += 512) {
            int n = i >> 5, ch = i & 31;
            int rr = n / RES, cc = n - rr * RES;
            const float* wd = dw_w + (size_t)(head * KD + ch) * 25;
            float acc = 0.f;
            #pragma unroll
            for (int dy = 0; dy < 5; ++dy) {
                int ry = rr + dy - 2;
                if (ry < 0 || ry >= RES) continue;
                #pragma unroll
                for (int dx = 0; dx < 5; ++dx) {
                    int cx = cc + dx - 2;
                    if (cx < 0 || cx >= RES) continue;
                    acc += qbuf[(ry * RES + cx) * QSTR + ch] * wd[dy * 5 + dx];
                }
            }
            int idx = head * KD + ch;
            float s  = dw_g[idx] * rsqrtf(dw_v[idx] + EPS);
            float tt = dw_bb[idx] - dw_m[idx] * s;
            qcv[n * QSTR + ch] = acc * s + tt;
        }
        __syncthreads();

        // ---- P4: att = qcv @ kbuf^T * scale + bias (M=64pad, N=64pad, K=32)
        {
            floatx4 sa[2];
            sa[0] = (floatx4){0.f, 0.f, 0.f, 0.f};
            sa[1] = (floatx4){0.f, 0.f, 0.f, 0.f};
            const float* ap = qcv + (mt * 16 + l15) * QSTR + quad * 8;
            short8 ah, al;
            split_pack8(*(const float4*)ap, *(const float4*)(ap + 4), ah, al);
            #pragma unroll
            for (int t = 0; t < 2; ++t) {
                const float* kp = kbuf + ((nh * 2 + t) * 16 + l15) * QSTR + quad * 8;
                short8 bh, bl;
                split_pack8(*(const float4*)kp, *(const float4*)(kp + 4), bh, bl);
                sa[t] = MFMA(ah, bh, sa[t]);
                sa[t] = MFMA(al, bh, sa[t]);
                sa[t] = MFMA(ah, bl, sa[t]);
            }
            const float scale = 0.17677669529663687f;
            #pragma unroll
            for (int t = 0; t < 2; ++t) {
                int nn = (nh * 2 + t) * 16 + l15;
                #pragma unroll
                for (int r = 0; r < 4; ++r) {
                    int row = mt * 16 + quad * 4 + r;
                    if (row < NPOS) {
                        if (nn < NPOS)
                            att[row * ASTR + nn] = sa[t][r] * scale
                                + attn_bias[head * NPOS + bias_idxs[row * NPOS + nn]];
                        else
                            att[row * ASTR + nn] = 0.f;   // K-pad for PV
                    }
                }
            }
        }
        __syncthreads();

        // ---- P5: softmax (8 lanes/row, shfl-xor reduce)
        {
            int row = tid >> 3, g = tid & 7;
            if (row < NPOS) {
                float mx = -1e30f;
                for (int n = g; n < NPOS; n += 8) mx = fmaxf(mx, att[row * ASTR + n]);
                #pragma unroll
                for (int d = 1; d < 8; d <<= 1) mx = fmaxf(mx, __shfl_xor(mx, d));
                float sm = 0.f;
                for (int n = g; n < NPOS; n += 8) {
                    float e = __expf(att[row * ASTR + n] - mx);
                    att[row * ASTR + n] = e;
                    sm += e;
                }
                #pragma unroll
                for (int d = 1; d < 8; d <<= 1) sm += __shfl_xor(sm, d);
                float inv = 1.f / sm;
                for (int n = g; n < NPOS; n += 8) att[row * ASTR + n] *= inv;
            }
        }
        __syncthreads();

        // ---- P6: feat = att @ v (M=64pad, N=128, K=64); att overlays feat:
        // read ALL att A-frags -> barrier -> MFMA -> write feat (fp32 LDS) and
        // h = bf16(relu(feat)) to global (d_out batch region).
        {
            short8 ah[2], al[2];
            #pragma unroll
            for (int ks = 0; ks < 2; ++ks) {
                const float* ap = att + (mt * 16 + l15) * ASTR + ks * 32 + quad * 8;
                split_pack8(*(const float4*)ap, *(const float4*)(ap + 4), ah[ks], al[ks]);
            }
            __syncthreads();   // all att reads done before feat overwrite
            floatx4 pa[4];
            #pragma unroll
            for (int t = 0; t < 4; ++t) pa[t] = (floatx4){0.f, 0.f, 0.f, 0.f};
            #pragma unroll
            for (int ks = 0; ks < 2; ++ks) {
                #pragma unroll
                for (int t = 0; t < 4; ++t) {
                    int off = ((nh * 4 + t) * 16 + l15) * VSTR + ks * 32 + quad * 8;
                    short8 bh = *(const short8*)(vTh + off);
                    short8 bl = *(const short8*)(vTl + off);
                    pa[t] = MFMA(ah[ks], bh, pa[t]);
                    pa[t] = MFMA(al[ks], bh, pa[t]);
                    pa[t] = MFMA(ah[ks], bl, pa[t]);
                }
            }
            #pragma unroll
            for (int t = 0; t < 4; ++t) {
                int d = (nh * 4 + t) * 16 + l15;
                #pragma unroll
                for (int r = 0; r < 4; ++r) {
                    int row = mt * 16 + quad * 4 + r;
                    if (row < NPOS) {
                        feat[row * FSTR + d] = pa[t][r];
                        __hip_bfloat162 hp =
                            __float22bfloat162_rn(make_float2(fmaxf(pa[t][r], 0.f), 0.f));
                        BU u; u.b = hp.x;
                        hb[row * CDIM + head * DDIM + d] = u.u;
                    }
                }
            }
        }
        __syncthreads();   // feat writes visible before next head's P1 read-modify-write
    }
}

// ===========================================================================
// Kernel 2: out = BN(h @ proj_w^T), h = bf16 in d_out's batch region (in place).
// One block/batch. Stage ALL of h into LDS first (barrier) -> in-place writes
// race-free. M=64pad x N=512 x K=512; 8 waves, wave owns 64 N-cols, po[16] accs.
// LDS 66560 B + total regs ~105 -> 2 blocks/CU.
// ===========================================================================
__global__ __launch_bounds__(512, 4) void proj_kernel(
    const float* __restrict__ pw,
    const float* __restrict__ proj_g, const float* __restrict__ proj_bb,
    const float* __restrict__ proj_m, const float* __restrict__ proj_v,
    float* __restrict__ io)
{
    __shared__ __align__(16) unsigned short hs[64 * HSTR];   // 66560 B

    const int b   = blockIdx.x;
    const int tid = threadIdx.x;
    float* iob = io + (size_t)b * NPOS * CDIM;
    const unsigned short* hsrc = (const unsigned short*)iob;

    // stage h (49 rows) + zero pad rows 49..63 (A pad -> discarded D rows, keep finite)
    for (int i = tid; i < NPOS * 64; i += 512) {
        int row = i >> 6, c8 = i & 63;
        *(short8*)(hs + row * HSTR + c8 * 8) = *(const short8*)(hsrc + row * 512 + c8 * 8);
    }
    for (int i = tid; i < 15 * 64; i += 512) {
        int row = 49 + (i >> 6), c8 = i & 63;
        *(short8*)(hs + row * HSTR + c8 * 8) = (short8){0,0,0,0,0,0,0,0};
    }
    __syncthreads();

    const int lane  = tid & 63;
    const int wid   = tid >> 6;
    const int quad  = lane >> 4;
    const int l15   = lane & 15;
    const int nbase = wid * 64;

    floatx4 po[16];
    #pragma unroll
    for (int t = 0; t < 16; ++t) po[t] = (floatx4){0.f, 0.f, 0.f, 0.f};

    for (int ks = 0; ks < 16; ++ks) {
        short8 af[4];
        #pragma unroll
        for (int mm = 0; mm < 4; ++mm)
            af[mm] = *(const short8*)(hs + (mm * 16 + l15) * HSTR + ks * 32 + quad * 8);
        #pragma unroll
        for (int j = 0; j < 4; ++j) {
            const float* wp = pw + (size_t)(nbase + j * 16 + l15) * CDIM + ks * 32 + quad * 8;
            short8 bf = pack_bf16x8(*(const float4*)wp, *(const float4*)(wp + 4));
            #pragma unroll
            for (int mm = 0; mm < 4; ++mm)
                po[mm * 4 + j] = MFMA(af[mm], bf, po[mm * 4 + j]);
        }
    }

    // BN epilogue + store (C/D layout: row = quad*4+r, col = l15)
    #pragma unroll
    for (int j = 0; j < 4; ++j) {
        int o = nbase + j * 16 + l15;
        float s  = proj_g[o] * rsqrtf(proj_v[o] + EPS);
        float tt = proj_bb[o] - proj_m[o] * s;
        #pragma unroll
        for (int mm = 0; mm < 4; ++mm) {
            #pragma unroll
            for (int r = 0; r < 4; ++r) {
                int row = mm * 16 + quad * 4 + r;
                if (row < NPOS)
                    iob[(size_t)row * CDIM + o] = po[mm * 4 + j][r] * s + tt;
            }
        }
    }
}

// ---------------------------------------------------------------------------
extern "C" void kernel_launch(void* const* d_in, const int* in_sizes, int n_in,
                              void* d_out, int out_size, void* d_ws, size_t ws_size,
                              hipStream_t stream) {
    const float* x      = (const float*)d_in[0];
    const float* qkv_w  = (const float*)d_in[1];
    const float* qkv_g  = (const float*)d_in[2];
    const float* qkv_b  = (const float*)d_in[3];
    const float* qkv_m  = (const float*)d_in[4];
    const float* qkv_v  = (const float*)d_in[5];
    const float* dw_w   = (const float*)d_in[6];
    const float* dw_g   = (const float*)d_in[7];
    const float* dw_b   = (const float*)d_in[8];
    const float* dw_m   = (const float*)d_in[9];
    const float* dw_v   = (const float*)d_in[10];
    const float* proj_w = (const float*)d_in[11];
    const float* proj_g = (const float*)d_in[12];
    const float* proj_b = (const float*)d_in[13];
    const float* proj_m = (const float*)d_in[14];
    const float* proj_v = (const float*)d_in[15];
    const float* attn_bias = (const float*)d_in[16];
    const int*   bias_idxs = (const int*)d_in[17];
    float* out = (float*)d_out;
    (void)d_ws; (void)ws_size;   // d_ws too small — unused.

    hipLaunchKernelGGL(cga_attn_kernel, dim3(BATCH), dim3(512), 0, stream,
        x, qkv_w, qkv_g, qkv_b, qkv_m, qkv_v,
        dw_w, dw_g, dw_b, dw_m, dw_v,
        attn_bias, bias_idxs, out);
    hipLaunchKernelGGL(proj_kernel, dim3(BATCH), dim3(512), 0, stream,
        proj_w, proj_g, proj_b, proj_m, proj_v, out);
}

// Round 7
// 1250.861 us; speedup vs baseline: 1.1841x; 1.0206x over previous
//
#include <hip/hip_runtime.h>
#include <hip/hip_bf16.h>

#define BATCH 2048
#define RES   7
#define NPOS  49
#define CDIM  512
#define HEADS 4
#define KD    32
#define DDIM  128
#define QO    192
#define EPS   1e-5f

// ---- LDS strides (element units). All fragment rows 16B-aligned; bank step
// per row = 4 dwords (gcd(stride_dwords,32)=4) -> worst 2-way = free.
#define FSTR 132   // feat [49][132] fp32
#define QSTR 36    // qbuf/qcv/kbuf [49][36] fp32
#define ASTR 68    // att  [49][68] fp32
#define VSTR 72    // vTh/vTl [128][72] bf16

// ---- Kernel-1 LDS layout (76848 B -> 2 blocks/CU on 160KB LDS)
#define OFF_QCV  0
#define OFF_ATT  7056
#define OFF_QBUF 25872
#define OFF_KBUF 32928
#define OFF_VTH  39984
#define OFF_VTL  58416
#define SMEM_SZ  76848

#define HSTR 520   // kernel-2 h LDS stride (shorts): 1040B rows, 16B-mult, gcd(260,32)=4

typedef __attribute__((ext_vector_type(8))) short short8;   // 8 bf16
typedef __attribute__((ext_vector_type(4))) float floatx4;  // 4 fp32 acc

union S8u { short8 v; __hip_bfloat162 h[4]; };
union BU  { __hip_bfloat16 b; unsigned short u; };

__device__ inline short8 pack_bf16x8(float4 a, float4 b) {
    S8u u;
    u.h[0] = __float22bfloat162_rn(make_float2(a.x, a.y));
    u.h[1] = __float22bfloat162_rn(make_float2(a.z, a.w));
    u.h[2] = __float22bfloat162_rn(make_float2(b.x, b.y));
    u.h[3] = __float22bfloat162_rn(make_float2(b.z, b.w));
    return u.v;
}

// Error-compensated split: x = hi + lo (both bf16). A*B ~= Ah*Bh + Al*Bh + Ah*Bl.
__device__ inline void split_pack8(float4 a, float4 b, short8& hi, short8& lo) {
    S8u H, L;
    float v0[8] = {a.x, a.y, a.z, a.w, b.x, b.y, b.z, b.w};
    #pragma unroll
    for (int p = 0; p < 4; ++p) {
        __hip_bfloat162 hp = __float22bfloat162_rn(make_float2(v0[2*p], v0[2*p+1]));
        float h0 = __bfloat162float(hp.x);
        float h1 = __bfloat162float(hp.y);
        H.h[p] = hp;
        L.h[p] = __float22bfloat162_rn(make_float2(v0[2*p] - h0, v0[2*p+1] - h1));
    }
    hi = H.v; lo = L.v;
}

#define MFMA(a, b, c) __builtin_amdgcn_mfma_f32_16x16x32_bf16((a), (b), (c), 0, 0, 0)

// ===========================================================================
// Kernel 1: cascade + QKV + conv + attention — BYTE-IDENTICAL to the R4
// harness-verified kernel (785us, occ 48%, no spill). One block/batch,
// 512 thr = 8 waves. Per head writes h = bf16(relu(feat)) into d_out's OWN
// batch region; kernel 2 consumes it in place.
// ===========================================================================
__global__ __launch_bounds__(512, 4) void cga_attn_kernel(
    const float* __restrict__ x,
    const float* __restrict__ qkv_w,
    const float* __restrict__ qkv_g,  const float* __restrict__ qkv_bb,
    const float* __restrict__ qkv_m,  const float* __restrict__ qkv_v,
    const float* __restrict__ dw_w,
    const float* __restrict__ dw_g,   const float* __restrict__ dw_bb,
    const float* __restrict__ dw_m,   const float* __restrict__ dw_v,
    const float* __restrict__ attn_bias,
    const int*   __restrict__ bias_idxs,
    float* __restrict__ out)
{
    __shared__ __align__(16) unsigned char smem[SMEM_SZ];
    float* feat = (float*)smem;                         // [49][FSTR]
    float* qcv  = (float*)(smem + OFF_QCV);             // [49][QSTR] (overlay in feat)
    float* att  = (float*)(smem + OFF_ATT);             // [49][ASTR] (overlay in feat)
    float* qbuf = (float*)(smem + OFF_QBUF);            // [49][QSTR]
    float* kbuf = (float*)(smem + OFF_KBUF);            // [49][QSTR]
    unsigned short* vTh = (unsigned short*)(smem + OFF_VTH);  // [128][VSTR]
    unsigned short* vTl = (unsigned short*)(smem + OFF_VTL);  // [128][VSTR]

    const int b    = blockIdx.x;
    const int tid  = threadIdx.x;
    const int lane = tid & 63;
    const int wid  = tid >> 6;
    const int quad = lane >> 4;
    const int l15  = lane & 15;
    const int mt   = wid & 3;
    const int nh   = wid >> 2;

    const float* xb = x + (size_t)b * NPOS * CDIM;
    unsigned short* hb = (unsigned short*)(out + (size_t)b * NPOS * CDIM);  // bf16 h, in-place

    // One-time: zero vT K-pad cols 49..63 (hi+lo) — stays zero all heads.
    for (int i = tid; i < 128 * 15; i += 512) {
        int d = i / 15, c = 49 + (i - d * 15);
        vTh[d * VSTR + c] = 0;
        vTl[d * VSTR + c] = 0;
    }

    for (int head = 0; head < HEADS; ++head) {
        // ---- P1: cascade feat update (feat = prev PV-out + x chunk)
        for (int i = tid; i < NPOS * (DDIM / 4); i += 512) {
            int n = i >> 5, c4 = i & 31;
            float4 xv = *(const float4*)(xb + n * CDIM + head * DDIM + c4 * 4);
            float* fp = feat + n * FSTR + c4 * 4;
            if (head == 0) { *(float4*)fp = xv; }
            else {
                float4 f = *(float4*)fp;
                f.x += xv.x; f.y += xv.y; f.z += xv.z; f.w += xv.w;
                *(float4*)fp = f;
            }
        }
        __syncthreads();

        // ---- P2: QKV = feat @ Wqkv^T (M=64pad, N=192, K=128), split-bf16 MFMA.
        {
            floatx4 qa[6];
            #pragma unroll
            for (int t = 0; t < 6; ++t) qa[t] = (floatx4){0.f, 0.f, 0.f, 0.f};
            for (int ks = 0; ks < 4; ++ks) {
                const float* ap = feat + (mt * 16 + l15) * FSTR + ks * 32 + quad * 8;
                short8 ah, al;
                split_pack8(*(const float4*)ap, *(const float4*)(ap + 4), ah, al);
                #pragma unroll
                for (int t = 0; t < 6; ++t) {
                    const float* wp = qkv_w
                        + (size_t)(head * QO + nh * 96 + t * 16 + l15) * DDIM + ks * 32 + quad * 8;
                    short8 bh, bl;
                    split_pack8(*(const float4*)wp, *(const float4*)(wp + 4), bh, bl);
                    qa[t] = MFMA(ah, bh, qa[t]);
                    qa[t] = MFMA(al, bh, qa[t]);
                    qa[t] = MFMA(ah, bl, qa[t]);
                }
            }
            // epilogue: BN then route q / k / v(split, transposed)
            #pragma unroll
            for (int t = 0; t < 6; ++t) {
                int o   = nh * 96 + t * 16 + l15;
                int idx = head * QO + o;
                float s  = qkv_g[idx] * rsqrtf(qkv_v[idx] + EPS);
                float tt = qkv_bb[idx] - qkv_m[idx] * s;
                #pragma unroll
                for (int r = 0; r < 4; ++r) {
                    int row = mt * 16 + quad * 4 + r;
                    if (row < NPOS) {
                        float y = qa[t][r] * s + tt;
                        if (o < KD)          qbuf[row * QSTR + o] = y;
                        else if (o < 2 * KD) kbuf[row * QSTR + (o - KD)] = y;
                        else {
                            int d = o - 2 * KD;
                            BU hu, lu;
                            __hip_bfloat162 hp = __float22bfloat162_rn(make_float2(y, 0.f));
                            hu.b = hp.x;
                            float hf = __bfloat162float(hp.x);
                            __hip_bfloat162 lp = __float22bfloat162_rn(make_float2(y - hf, 0.f));
                            lu.b = lp.x;
                            vTh[d * VSTR + row] = hu.u;
                            vTl[d * VSTR + row] = lu.u;
                        }
                    }
                }
            }
        }
        __syncthreads();

        // ---- P3: depthwise 5x5 conv + BN -> qcv
        for (int i = tid; i < NPOS * KD; i += 512) {
            int n = i >> 5, ch = i & 31;
            int rr = n / RES, cc = n - rr * RES;
            const float* wd = dw_w + (size_t)(head * KD + ch) * 25;
            float acc = 0.f;
            #pragma unroll
            for (int dy = 0; dy < 5; ++dy) {
                int ry = rr + dy - 2;
                if (ry < 0 || ry >= RES) continue;
                #pragma unroll
                for (int dx = 0; dx < 5; ++dx) {
                    int cx = cc + dx - 2;
                    if (cx < 0 || cx >= RES) continue;
                    acc += qbuf[(ry * RES + cx) * QSTR + ch] * wd[dy * 5 + dx];
                }
            }
            int idx = head * KD + ch;
            float s  = dw_g[idx] * rsqrtf(dw_v[idx] + EPS);
            float tt = dw_bb[idx] - dw_m[idx] * s;
            qcv[n * QSTR + ch] = acc * s + tt;
        }
        __syncthreads();

        // ---- P4: att = qcv @ kbuf^T * scale + bias (M=64pad, N=64pad, K=32)
        {
            floatx4 sa[2];
            sa[0] = (floatx4){0.f, 0.f, 0.f, 0.f};
            sa[1] = (floatx4){0.f, 0.f, 0.f, 0.f};
            const float* ap = qcv + (mt * 16 + l15) * QSTR + quad * 8;
            short8 ah, al;
            split_pack8(*(const float4*)ap, *(const float4*)(ap + 4), ah, al);
            #pragma unroll
            for (int t = 0; t < 2; ++t) {
                const float* kp = kbuf + ((nh * 2 + t) * 16 + l15) * QSTR + quad * 8;
                short8 bh, bl;
                split_pack8(*(const float4*)kp, *(const float4*)(kp + 4), bh, bl);
                sa[t] = MFMA(ah, bh, sa[t]);
                sa[t] = MFMA(al, bh, sa[t]);
                sa[t] = MFMA(ah, bl, sa[t]);
            }
            const float scale = 0.17677669529663687f;
            #pragma unroll
            for (int t = 0; t < 2; ++t) {
                int nn = (nh * 2 + t) * 16 + l15;
                #pragma unroll
                for (int r = 0; r < 4; ++r) {
                    int row = mt * 16 + quad * 4 + r;
                    if (row < NPOS) {
                        if (nn < NPOS)
                            att[row * ASTR + nn] = sa[t][r] * scale
                                + attn_bias[head * NPOS + bias_idxs[row * NPOS + nn]];
                        else
                            att[row * ASTR + nn] = 0.f;   // K-pad for PV
                    }
                }
            }
        }
        __syncthreads();

        // ---- P5: softmax (8 lanes/row, shfl-xor reduce)
        {
            int row = tid >> 3, g = tid & 7;
            if (row < NPOS) {
                float mx = -1e30f;
                for (int n = g; n < NPOS; n += 8) mx = fmaxf(mx, att[row * ASTR + n]);
                #pragma unroll
                for (int d = 1; d < 8; d <<= 1) mx = fmaxf(mx, __shfl_xor(mx, d));
                float sm = 0.f;
                for (int n = g; n < NPOS; n += 8) {
                    float e = __expf(att[row * ASTR + n] - mx);
                    att[row * ASTR + n] = e;
                    sm += e;
                }
                #pragma unroll
                for (int d = 1; d < 8; d <<= 1) sm += __shfl_xor(sm, d);
                float inv = 1.f / sm;
                for (int n = g; n < NPOS; n += 8) att[row * ASTR + n] *= inv;
            }
        }
        __syncthreads();

        // ---- P6: feat = att @ v (M=64pad, N=128, K=64); att overlays feat:
        // read ALL att A-frags -> barrier -> MFMA -> write feat (fp32 LDS) and
        // h = bf16(relu(feat)) to global (d_out batch region).
        {
            short8 ah[2], al[2];
            #pragma unroll
            for (int ks = 0; ks < 2; ++ks) {
                const float* ap = att + (mt * 16 + l15) * ASTR + ks * 32 + quad * 8;
                split_pack8(*(const float4*)ap, *(const float4*)(ap + 4), ah[ks], al[ks]);
            }
            __syncthreads();   // all att reads done before feat overwrite
            floatx4 pa[4];
            #pragma unroll
            for (int t = 0; t < 4; ++t) pa[t] = (floatx4){0.f, 0.f, 0.f, 0.f};
            #pragma unroll
            for (int ks = 0; ks < 2; ++ks) {
                #pragma unroll
                for (int t = 0; t < 4; ++t) {
                    int off = ((nh * 4 + t) * 16 + l15) * VSTR + ks * 32 + quad * 8;
                    short8 bh = *(const short8*)(vTh + off);
                    short8 bl = *(const short8*)(vTl + off);
                    pa[t] = MFMA(ah[ks], bh, pa[t]);
                    pa[t] = MFMA(al[ks], bh, pa[t]);
                    pa[t] = MFMA(ah[ks], bl, pa[t]);
                }
            }
            #pragma unroll
            for (int t = 0; t < 4; ++t) {
                int d = (nh * 4 + t) * 16 + l15;
                #pragma unroll
                for (int r = 0; r < 4; ++r) {
                    int row = mt * 16 + quad * 4 + r;
                    if (row < NPOS) {
                        feat[row * FSTR + d] = pa[t][r];
                        __hip_bfloat162 hp =
                            __float22bfloat162_rn(make_float2(fmaxf(pa[t][r], 0.f), 0.f));
                        BU u; u.b = hp.x;
                        hb[row * CDIM + head * DDIM + d] = u.u;
                    }
                }
            }
        }
        __syncthreads();   // feat writes visible before next head's P1 read-modify-write
    }
}

// ===========================================================================
// Kernel 2: out = BN(h @ proj_w^T), h = bf16 in d_out's batch region (in place).
// One block/batch. Stage ALL of h into LDS first (barrier) -> global h is dead
// afterward -> in-place out writes race-free (per-batch block ownership).
// R4 lesson: po[16] (64 AGPR) under the (512,4) 128-reg cap spilled to scratch
// in the K-loop -> ~490us. Fix: TWO N-passes (256 cols each) with po[8]
// (32 AGPR); peak live ~75 regs -> no spill, still 2 blocks/CU.
// ===========================================================================
__global__ __launch_bounds__(512, 4) void proj_kernel(
    const float* __restrict__ pw,
    const float* __restrict__ proj_g, const float* __restrict__ proj_bb,
    const float* __restrict__ proj_m, const float* __restrict__ proj_v,
    float* __restrict__ io)
{
    __shared__ __align__(16) unsigned short hs[64 * HSTR];   // 66560 B

    const int b   = blockIdx.x;
    const int tid = threadIdx.x;
    float* iob = io + (size_t)b * NPOS * CDIM;
    const unsigned short* hsrc = (const unsigned short*)iob;

    // stage h (49 rows) + zero pad rows 49..63 (A pad -> discarded D rows, keep finite)
    for (int i = tid; i < NPOS * 64; i += 512) {
        int row = i >> 6, c8 = i & 63;
        *(short8*)(hs + row * HSTR + c8 * 8) = *(const short8*)(hsrc + row * 512 + c8 * 8);
    }
    for (int i = tid; i < 15 * 64; i += 512) {
        int row = 49 + (i >> 6), c8 = i & 63;
        *(short8*)(hs + row * HSTR + c8 * 8) = (short8){0,0,0,0,0,0,0,0};
    }
    __syncthreads();

    const int lane  = tid & 63;
    const int wid   = tid >> 6;
    const int quad  = lane >> 4;
    const int l15   = lane & 15;

    for (int pass = 0; pass < 2; ++pass) {
        const int nbase = pass * 256 + wid * 32;   // wave owns 32 N-cols this pass

        floatx4 po[8];   // 4 M-tiles x 2 N-tiles
        #pragma unroll
        for (int t = 0; t < 8; ++t) po[t] = (floatx4){0.f, 0.f, 0.f, 0.f};

        for (int ks = 0; ks < 16; ++ks) {
            short8 af[4];
            #pragma unroll
            for (int mm = 0; mm < 4; ++mm)
                af[mm] = *(const short8*)(hs + (mm * 16 + l15) * HSTR + ks * 32 + quad * 8);
            #pragma unroll
            for (int j = 0; j < 2; ++j) {
                const float* wp = pw + (size_t)(nbase + j * 16 + l15) * CDIM + ks * 32 + quad * 8;
                short8 bf = pack_bf16x8(*(const float4*)wp, *(const float4*)(wp + 4));
                #pragma unroll
                for (int mm = 0; mm < 4; ++mm)
                    po[mm * 2 + j] = MFMA(af[mm], bf, po[mm * 2 + j]);
            }
        }

        // BN epilogue + store (C/D layout: row = quad*4+r, col = l15)
        #pragma unroll
        for (int j = 0; j < 2; ++j) {
            int o = nbase + j * 16 + l15;
            float s  = proj_g[o] * rsqrtf(proj_v[o] + EPS);
            float tt = proj_bb[o] - proj_m[o] * s;
            #pragma unroll
            for (int mm = 0; mm < 4; ++mm) {
                #pragma unroll
                for (int r = 0; r < 4; ++r) {
                    int row = mm * 16 + quad * 4 + r;
                    if (row < NPOS)
                        iob[(size_t)row * CDIM + o] = po[mm * 2 + j][r] * s + tt;
                }
            }
        }
    }
}

// ---------------------------------------------------------------------------
extern "C" void kernel_launch(void* const* d_in, const int* in_sizes, int n_in,
                              void* d_out, int out_size, void* d_ws, size_t ws_size,
                              hipStream_t stream) {
    const float* x      = (const float*)d_in[0];
    const float* qkv_w  = (const float*)d_in[1];
    const float* qkv_g  = (const float*)d_in[2];
    const float* qkv_b  = (const float*)d_in[3];
    const float* qkv_m  = (const float*)d_in[4];
    const float* qkv_v  = (const float*)d_in[5];
    const float* dw_w   = (const float*)d_in[6];
    const float* dw_g   = (const float*)d_in[7];
    const float* dw_b   = (const float*)d_in[8];
    const float* dw_m   = (const float*)d_in[9];
    const float* dw_v   = (const float*)d_in[10];
    const float* proj_w = (const float*)d_in[11];
    const float* proj_g = (const float*)d_in[12];
    const float* proj_b = (const float*)d_in[13];
    const float* proj_m = (const float*)d_in[14];
    const float* proj_v = (const float*)d_in[15];
    const float* attn_bias = (const float*)d_in[16];
    const int*   bias_idxs = (const int*)d_in[17];
    float* out = (float*)d_out;
    (void)d_ws; (void)ws_size;   // d_ws too small — unused.

    hipLaunchKernelGGL(cga_attn_kernel, dim3(BATCH), dim3(512), 0, stream,
        x, qkv_w, qkv_g, qkv_b, qkv_m, qkv_v,
        dw_w, dw_g, dw_b, dw_m, dw_v,
        attn_bias, bias_idxs, out);
    hipLaunchKernelGGL(proj_kernel, dim3(BATCH), dim3(512), 0, stream,
        proj_w, proj_g, proj_b, proj_m, proj_v, out);
}